// Round 4
// baseline (2953.314 us; speedup 1.0000x reference)
//
#include <hip/hip_runtime.h>

#define D 128
#define LN_EPS 1e-5f
#define BUCKET_NODES 128
#define BUCKET_SHIFT 7
#define EDGE_CAP 4096          // avg 2046 edges/bucket, 6-sigma ~2320; 2x headroom
#define K2_THREADS 512
#define K2_EPT 16              // 8192 edges per block
#define K3_THREADS 1024

// split bf16 packing: word f of a row holds (feat f, feat f+64)
__device__ inline unsigned int pack_b2(float a, float b) {
    unsigned ua = __float_as_uint(a);
    unsigned ub = __float_as_uint(b);
    unsigned pa = (ua + 0x7fffu + ((ua >> 16) & 1u)) >> 16;
    unsigned pb = (ub + 0x7fffu + ((ub >> 16) & 1u)) & 0xffff0000u;
    return pa | pb;
}

// ---- K1: x (f32, natural order) -> xb (packed bf16, split layout) ----
__global__ void conv_kernel(const float* __restrict__ x,
                            unsigned int* __restrict__ xb, int nwords) {
    int i = blockIdx.x * blockDim.x + threadIdx.x;
    if (i < nwords) {
        int node = i >> 6, f = i & 63;
        float a = x[(size_t)node * D + f];
        float b = x[(size_t)node * D + 64 + f];
        xb[i] = pack_b2(a, b);
    }
}

// ---- K2: bucket edges by dst>>7 into fixed-capacity slices ----
// per-block LDS hist -> one reservation atomic per (block,bucket) -> writes
// land in per-block contiguous runs (single-XCD lines, L2-mergeable).
__global__ void bucket_fill_kernel(const int* __restrict__ src,
                                   const int* __restrict__ dst,
                                   const float* __restrict__ val,
                                   int* __restrict__ gcnt,
                                   uint2* __restrict__ edges,
                                   int E, int nbuckets) {
    __shared__ int lcnt[1024];
    __shared__ int lbase[1024];
    for (int i = threadIdx.x; i < nbuckets; i += K2_THREADS) lcnt[i] = 0;
    __syncthreads();

    int base = blockIdx.x * (K2_THREADS * K2_EPT);
    unsigned int w0[K2_EPT];
    float        w1[K2_EPT];
    int          br[K2_EPT];   // (bucket<<16)|rank, or -1
    #pragma unroll
    for (int r = 0; r < K2_EPT; ++r) {
        int e = base + r * K2_THREADS + threadIdx.x;
        if (e < E) {
            int d = dst[e];
            int b = d >> BUCKET_SHIFT;
            int rk = atomicAdd(&lcnt[b], 1);
            w0[r] = (unsigned)src[e] | ((unsigned)(d & (BUCKET_NODES - 1)) << 20);
            w1[r] = val[e];
            br[r] = (b << 16) | rk;
        } else {
            br[r] = -1;
        }
    }
    __syncthreads();
    for (int i = threadIdx.x; i < nbuckets; i += K2_THREADS) {
        int c = lcnt[i];
        lbase[i] = c ? atomicAdd(&gcnt[i], c) : 0;
    }
    __syncthreads();
    #pragma unroll
    for (int r = 0; r < K2_EPT; ++r) {
        if (br[r] >= 0) {
            int b  = br[r] >> 16;
            int rk = br[r] & 0xffff;
            edges[(size_t)b * EDGE_CAP + lbase[b] + rk] =
                make_uint2(w0[r], __float_as_uint(w1[r]));
        }
    }
}

// ---- K3: per-bucket LDS scatter-add + diag-w + LayerNorm (+ReLU) ----
// block = bucket (128 nodes), 64KB LDS accumulator, 16 waves.
// lane holds feats (lane, lane+64): LDS atomic addrs are 2-way bank-aliased (free).
__global__ __launch_bounds__(K3_THREADS)
void agg_ln_kernel(const unsigned int* __restrict__ h2,
                   const int* __restrict__ gcnt,
                   const uint2* __restrict__ edges,
                   const float* __restrict__ w,
                   const float* __restrict__ g,
                   const float* __restrict__ bb,
                   float* __restrict__ out_f32,
                   unsigned int* __restrict__ out_b2,
                   int N, int mode) {
    __shared__ float acc[BUCKET_NODES * D];   // 64 KB
    int b    = blockIdx.x;
    int lane = threadIdx.x & 63;
    int wid  = threadIdx.x >> 6;              // 0..15

    for (int i = threadIdx.x; i < BUCKET_NODES * D; i += K3_THREADS) acc[i] = 0.0f;
    __syncthreads();

    int cnt = gcnt[b];
    const uint2* ep = edges + (size_t)b * EDGE_CAP;

    for (int cbase = wid * 64; cbase < cnt; cbase += 16 * 64) {
        int m = min(64, cnt - cbase);
        unsigned int e0 = 0u, e1 = 0u;
        if (lane < m) { uint2 t = ep[cbase + lane]; e0 = t.x; e1 = t.y; }
        for (int j = 0; j < m; ++j) {
            unsigned a0 = (unsigned)__shfl((int)e0, j, 64);
            float v = __uint_as_float((unsigned)__shfl((int)e1, j, 64));
            int s  = a0 & 0xfffff;
            int dl = a0 >> 20;
            unsigned hw = h2[(size_t)s * 64 + lane];
            float hx = __uint_as_float((hw & 0xffffu) << 16);
            float hy = __uint_as_float(hw & 0xffff0000u);
            atomicAdd(&acc[dl * D + lane],      v * hx);
            atomicAdd(&acc[dl * D + 64 + lane], v * hy);
        }
    }
    __syncthreads();

    // LN: 128 nodes / 16 waves = 8 nodes per wave
    int node0 = b << BUCKET_SHIFT;
    float wx = w[lane], wy = w[64 + lane];
    float gx = g[lane], gy = g[64 + lane];
    float bx = bb[lane], by = bb[64 + lane];
    for (int ni = wid; ni < BUCKET_NODES; ni += 16) {
        int n = node0 + ni;
        if (n >= N) break;
        float ax = acc[ni * D + lane] * wx;
        float ay = acc[ni * D + 64 + lane] * wy;

        float sum = ax + ay;
        #pragma unroll
        for (int off = 32; off > 0; off >>= 1) sum += __shfl_down(sum, off, 64);
        sum = __shfl(sum, 0, 64);
        float mu = sum * (1.0f / D);

        float dx = ax - mu, dy = ay - mu;
        float sq = dx * dx + dy * dy;
        #pragma unroll
        for (int off = 32; off > 0; off >>= 1) sq += __shfl_down(sq, off, 64);
        sq = __shfl(sq, 0, 64);
        float rstd = rsqrtf(sq * (1.0f / D) + LN_EPS);

        float ox = dx * rstd * gx + bx;
        float oy = dy * rstd * gy + by;
        if (mode == 1) {
            ox = fmaxf(ox, 0.0f);
            oy = fmaxf(oy, 0.0f);
            out_b2[(size_t)n * 64 + lane] = pack_b2(ox, oy);
        } else {
            out_f32[(size_t)n * D + lane]      = ox;
            out_f32[(size_t)n * D + 64 + lane] = oy;
        }
    }
}

extern "C" void kernel_launch(void* const* d_in, const int* in_sizes, int n_in,
                              void* d_out, int out_size, void* d_ws, size_t ws_size,
                              hipStream_t stream) {
    const float* x    = (const float*)d_in[0];
    const int*   esrc = (const int*)d_in[1];
    const int*   edst = (const int*)d_in[2];
    const float* eval_= (const float*)d_in[3];
    const float* w1   = (const float*)d_in[4];
    const float* w2   = (const float*)d_in[5];
    const float* g1   = (const float*)d_in[6];
    const float* b1   = (const float*)d_in[7];
    const float* g2   = (const float*)d_in[8];
    const float* b2   = (const float*)d_in[9];
    float* out = (float*)d_out;

    const int N = in_sizes[0] / D;   // 100000
    const int E = in_sizes[1];       // 1600000
    const int nbuckets = (N + BUCKET_NODES - 1) >> BUCKET_SHIFT;   // 782

    // workspace: xb (25.6MB) + hb (25.6MB) + edges (25.6MB) + gcnt
    unsigned int* xb    = (unsigned int*)d_ws;
    unsigned int* hb    = xb + (size_t)N * 64;
    uint2*        edges = (uint2*)(hb + (size_t)N * 64);
    int*          gcnt  = (int*)(edges + (size_t)nbuckets * EDGE_CAP);

    const int nwords = N * 64;
    const int cgrid  = (nwords + 255) / 256;
    const int k2grid = (E + K2_THREADS * K2_EPT - 1) / (K2_THREADS * K2_EPT);

    hipMemsetAsync(gcnt, 0, (size_t)nbuckets * sizeof(int), stream);
    conv_kernel<<<cgrid, 256, 0, stream>>>(x, xb, nwords);
    bucket_fill_kernel<<<k2grid, K2_THREADS, 0, stream>>>(esrc, edst, eval_,
                                                          gcnt, edges, E, nbuckets);
    // layer 1: gather(xb)*w1 -> LN -> ReLU -> hb (bf16 split)
    agg_ln_kernel<<<nbuckets, K3_THREADS, 0, stream>>>(xb, gcnt, edges,
                                                       w1, g1, b1, nullptr, hb, N, 1);
    // layer 2: gather(hb)*w2 -> LN -> out (f32)
    agg_ln_kernel<<<nbuckets, K3_THREADS, 0, stream>>>(hb, gcnt, edges,
                                                       w2, g2, b2, out, nullptr, N, 0);
}

// Round 5
// 392.673 us; speedup vs baseline: 7.5211x; 7.5211x over previous
//
#include <hip/hip_runtime.h>

#define D 128
#define LN_EPS 1e-5f
#define BUCKET_NODES 128
#define BUCKET_SHIFT 7
#define EDGE_CAP 4096          // avg ~2048 edges/bucket, std ~45; 45-sigma headroom
#define K2_THREADS 512
#define K2_EPT 16              // 8192 edges per fill block
#define SORT_THREADS 512
#define SORT_EPT 8             // 4096 / 512

// split bf16 packing: word f of a row holds (feat f, feat f+64)
__device__ inline unsigned int pack_b2(float a, float b) {
    unsigned ua = __float_as_uint(a);
    unsigned ub = __float_as_uint(b);
    unsigned pa = (ua + 0x7fffu + ((ua >> 16) & 1u)) >> 16;
    unsigned pb = (ub + 0x7fffu + ((ub >> 16) & 1u)) & 0xffff0000u;
    return pa | pb;
}

// ---- K1: x (f32) -> xb (packed bf16, split layout) ----
__global__ void conv_kernel(const float* __restrict__ x,
                            unsigned int* __restrict__ xb, int nwords) {
    int i = blockIdx.x * blockDim.x + threadIdx.x;
    if (i < nwords) {
        int node = i >> 6, f = i & 63;
        xb[i] = pack_b2(x[(size_t)node * D + f], x[(size_t)node * D + 64 + f]);
    }
}

// ---- K2: coarse-bucket edges by dst>>7 into fixed-capacity slices ----
// per-block LDS hist -> one reservation atomic per (block,bucket) -> per-block
// contiguous write runs (line-dense, ~16MB instead of 100MB scattered).
__global__ void bucket_fill_kernel(const int* __restrict__ src,
                                   const int* __restrict__ dst,
                                   const float* __restrict__ val,
                                   int* __restrict__ gcnt,
                                   uint2* __restrict__ edges,
                                   int E, int nbuckets) {
    __shared__ int lcnt[1024];
    __shared__ int lbase[1024];
    for (int i = threadIdx.x; i < nbuckets; i += K2_THREADS) lcnt[i] = 0;
    __syncthreads();

    int base = blockIdx.x * (K2_THREADS * K2_EPT);
    unsigned int w0[K2_EPT];
    float        w1[K2_EPT];
    int          br[K2_EPT];   // (bucket<<16)|rank, or -1
    #pragma unroll
    for (int r = 0; r < K2_EPT; ++r) {
        int e = base + r * K2_THREADS + threadIdx.x;
        if (e < E) {
            int d = dst[e];
            int b = d >> BUCKET_SHIFT;
            int rk = atomicAdd(&lcnt[b], 1);
            w0[r] = (unsigned)src[e] | ((unsigned)(d & (BUCKET_NODES - 1)) << 20);
            w1[r] = val[e];
            br[r] = (b << 16) | rk;
        } else {
            br[r] = -1;
        }
    }
    __syncthreads();
    for (int i = threadIdx.x; i < nbuckets; i += K2_THREADS) {
        int c = lcnt[i];
        lbase[i] = c ? atomicAdd(&gcnt[i], c) : 0;
    }
    __syncthreads();
    #pragma unroll
    for (int r = 0; r < K2_EPT; ++r) {
        if (br[r] >= 0) {
            int b  = br[r] >> 16;
            int rk = br[r] & 0xffff;
            edges[(size_t)b * EDGE_CAP + lbase[b] + rk] =
                make_uint2(w0[r], __float_as_uint(w1[r]));
        }
    }
}

// ---- K3: counting-sort each bucket slice by node, in place; emit deg/offsets ----
__global__ __launch_bounds__(SORT_THREADS)
void bucket_sort_kernel(uint2* __restrict__ edges,
                        const int* __restrict__ gcnt,
                        int* __restrict__ deg,
                        int* __restrict__ offsets,
                        int N) {
    __shared__ int hist[BUCKET_NODES];
    __shared__ int scan[BUCKET_NODES];
    int b = blockIdx.x;
    int cnt = gcnt[b];
    uint2* ep = edges + (size_t)b * EDGE_CAP;

    if (threadIdx.x < BUCKET_NODES) hist[threadIdx.x] = 0;
    __syncthreads();

    uint2 ed[SORT_EPT];
    int   rk[SORT_EPT];
    int   dl[SORT_EPT];
    #pragma unroll
    for (int r = 0; r < SORT_EPT; ++r) {
        int i = r * SORT_THREADS + threadIdx.x;
        if (i < cnt) {
            uint2 t = ep[i];
            int d = (int)(t.x >> 20);
            ed[r] = t;
            dl[r] = d;
            rk[r] = atomicAdd(&hist[d], 1);
        } else {
            dl[r] = -1;
        }
    }
    __syncthreads();

    // inclusive Hillis-Steele scan of hist -> scan (128 entries)
    if (threadIdx.x < BUCKET_NODES) scan[threadIdx.x] = hist[threadIdx.x];
    __syncthreads();
    #pragma unroll
    for (int off = 1; off < BUCKET_NODES; off <<= 1) {
        int v = 0;
        if (threadIdx.x < BUCKET_NODES && threadIdx.x >= off) v = scan[threadIdx.x - off];
        __syncthreads();
        if (threadIdx.x < BUCKET_NODES) scan[threadIdx.x] += v;
        __syncthreads();
    }

    int node0 = b << BUCKET_SHIFT;
    if (threadIdx.x < BUCKET_NODES) {
        int n = node0 + threadIdx.x;
        if (n < N) {
            deg[n]     = hist[threadIdx.x];
            offsets[n] = b * EDGE_CAP + scan[threadIdx.x] - hist[threadIdx.x];
        }
    }
    __syncthreads();

    #pragma unroll
    for (int r = 0; r < SORT_EPT; ++r) {
        if (dl[r] >= 0) {
            int p = scan[dl[r]] - hist[dl[r]] + rk[r];   // exclusive base + rank
            ep[p] = ed[r];
        }
    }
}

// ---- K4: fused gather + diag-w + LayerNorm (+ReLU), wave per node ----
// lane holds feats (lane, lane+64) via split bf16 words.
__global__ void gather_ln_kernel(const unsigned int* __restrict__ h2,
                                 const int* __restrict__ offsets,
                                 const int* __restrict__ deg,
                                 const uint2* __restrict__ edge_s,
                                 const float* __restrict__ w,
                                 const float* __restrict__ g,
                                 const float* __restrict__ bb,
                                 float* __restrict__ out_f32,
                                 unsigned int* __restrict__ out_b2,
                                 int N, int mode) {
    int node = blockIdx.x * (blockDim.x >> 6) + (threadIdx.x >> 6);
    int lane = threadIdx.x & 63;
    if (node >= N) return;

    int start = offsets[node];
    int cnt   = deg[node];

    float accx = 0.0f, accy = 0.0f;
    for (int base = 0; base < cnt; base += 64) {
        int m = min(64, cnt - base);
        unsigned int e0 = 0u, e1 = 0u;
        if (lane < m) { uint2 t = edge_s[start + base + lane]; e0 = t.x; e1 = t.y; }
        for (int j = 0; j < m; ++j) {
            unsigned a0 = (unsigned)__shfl((int)e0, j, 64);
            float v = __uint_as_float((unsigned)__shfl((int)e1, j, 64));
            int s = (int)(a0 & 0xfffff);
            unsigned hw = h2[(size_t)s * 64 + lane];
            float hx = __uint_as_float((hw & 0xffffu) << 16);
            float hy = __uint_as_float(hw & 0xffff0000u);
            accx = fmaf(v, hx, accx);
            accy = fmaf(v, hy, accy);
        }
    }

    accx *= w[lane];
    accy *= w[64 + lane];

    float sum = accx + accy;
    #pragma unroll
    for (int off = 32; off > 0; off >>= 1) sum += __shfl_down(sum, off, 64);
    sum = __shfl(sum, 0, 64);
    float mu = sum * (1.0f / D);

    float dx = accx - mu, dy = accy - mu;
    float sq = dx * dx + dy * dy;
    #pragma unroll
    for (int off = 32; off > 0; off >>= 1) sq += __shfl_down(sq, off, 64);
    sq = __shfl(sq, 0, 64);
    float rstd = rsqrtf(sq * (1.0f / D) + LN_EPS);

    float ox = dx * rstd * g[lane]      + bb[lane];
    float oy = dy * rstd * g[64 + lane] + bb[64 + lane];
    if (mode == 1) {
        ox = fmaxf(ox, 0.0f);
        oy = fmaxf(oy, 0.0f);
        out_b2[(size_t)node * 64 + lane] = pack_b2(ox, oy);
    } else {
        out_f32[(size_t)node * D + lane]      = ox;
        out_f32[(size_t)node * D + 64 + lane] = oy;
    }
}

extern "C" void kernel_launch(void* const* d_in, const int* in_sizes, int n_in,
                              void* d_out, int out_size, void* d_ws, size_t ws_size,
                              hipStream_t stream) {
    const float* x    = (const float*)d_in[0];
    const int*   esrc = (const int*)d_in[1];
    const int*   edst = (const int*)d_in[2];
    const float* eval_= (const float*)d_in[3];
    const float* w1   = (const float*)d_in[4];
    const float* w2   = (const float*)d_in[5];
    const float* g1   = (const float*)d_in[6];
    const float* b1   = (const float*)d_in[7];
    const float* g2   = (const float*)d_in[8];
    const float* b2   = (const float*)d_in[9];
    float* out = (float*)d_out;

    const int N = in_sizes[0] / D;   // 100000
    const int E = in_sizes[1];       // 1600000
    const int nbuckets = (N + BUCKET_NODES - 1) >> BUCKET_SHIFT;   // 782

    // workspace: xb 25.6MB + hb 25.6MB + edges 25.6MB + gcnt/deg/offsets ~1MB
    unsigned int* xb      = (unsigned int*)d_ws;
    unsigned int* hb      = xb + (size_t)N * 64;
    uint2*        edges   = (uint2*)(hb + (size_t)N * 64);
    int*          gcnt    = (int*)(edges + (size_t)nbuckets * EDGE_CAP);
    int*          deg     = gcnt + nbuckets;
    int*          offsets = deg + N;

    const int nwords = N * 64;
    const int cgrid  = (nwords + 255) / 256;
    const int k2grid = (E + K2_THREADS * K2_EPT - 1) / (K2_THREADS * K2_EPT);
    const int ggrid  = (N + 3) / 4;   // 4 waves/block, wave per node

    hipMemsetAsync(gcnt, 0, (size_t)nbuckets * sizeof(int), stream);
    conv_kernel<<<cgrid, 256, 0, stream>>>(x, xb, nwords);
    bucket_fill_kernel<<<k2grid, K2_THREADS, 0, stream>>>(esrc, edst, eval_,
                                                          gcnt, edges, E, nbuckets);
    bucket_sort_kernel<<<nbuckets, SORT_THREADS, 0, stream>>>(edges, gcnt,
                                                              deg, offsets, N);
    // layer 1: gather(xb)*w1 -> LN -> ReLU -> hb (bf16 split)
    gather_ln_kernel<<<ggrid, 256, 0, stream>>>(xb, offsets, deg, edges,
                                                w1, g1, b1, nullptr, hb, N, 1);
    // layer 2: gather(hb)*w2 -> LN -> out (f32)
    gather_ln_kernel<<<ggrid, 256, 0, stream>>>(hb, offsets, deg, edges,
                                                w2, g2, b2, out, nullptr, N, 0);
}

// Round 6
// 308.526 us; speedup vs baseline: 9.5723x; 1.2727x over previous
//
#include <hip/hip_runtime.h>

#define D 128
#define LN_EPS 1e-5f
#define BUCKET_NODES 128
#define BUCKET_SHIFT 7
#define EDGE_CAP 4096          // avg ~2046 edges/bucket, std ~45; huge headroom
#define FUSE_THREADS 512
#define K2_EPT 16              // 8192 edges per fill block
#define SORT_THREADS 512
#define SORT_EPT 8             // 4096 / 512

// split bf16 packing: word f of a row holds (feat f, feat f+64)
__device__ inline unsigned int pack_b2(float a, float b) {
    unsigned ua = __float_as_uint(a);
    unsigned ub = __float_as_uint(b);
    unsigned pa = (ua + 0x7fffu + ((ua >> 16) & 1u)) >> 16;
    unsigned pb = (ub + 0x7fffu + ((ub >> 16) & 1u)) & 0xffff0000u;
    return pa | pb;
}
__device__ inline float lo_b2(unsigned u) { return __uint_as_float((u & 0xffffu) << 16); }
__device__ inline float hi_b2(unsigned u) { return __uint_as_float(u & 0xffff0000u); }

// ---- K1: stitched  conv (x f32 -> xb split-bf16)  +  coarse bucket fill ----
__global__ __launch_bounds__(FUSE_THREADS)
void conv_fill_kernel(const float* __restrict__ x, unsigned int* __restrict__ xb,
                      int nwords, int conv_blocks,
                      const int* __restrict__ src, const int* __restrict__ dst,
                      const float* __restrict__ val,
                      int* __restrict__ gcnt, uint2* __restrict__ edges,
                      int E, int nbuckets) {
    if ((int)blockIdx.x < conv_blocks) {
        int i = blockIdx.x * FUSE_THREADS + threadIdx.x;
        if (i < nwords) {
            int node = i >> 6, f = i & 63;
            xb[i] = pack_b2(x[(size_t)node * D + f], x[(size_t)node * D + 64 + f]);
        }
        return;
    }
    // ---- fill part: per-block LDS hist -> one reservation atomic per bucket ->
    //      per-block contiguous write runs (line-dense)
    __shared__ int lcnt[1024];
    __shared__ int lbase[1024];
    int fb = (int)blockIdx.x - conv_blocks;
    for (int i = threadIdx.x; i < nbuckets; i += FUSE_THREADS) lcnt[i] = 0;
    __syncthreads();

    int base = fb * (FUSE_THREADS * K2_EPT);
    unsigned int w0[K2_EPT];
    float        w1[K2_EPT];
    int          br[K2_EPT];   // (bucket<<16)|rank, or -1
    #pragma unroll
    for (int r = 0; r < K2_EPT; ++r) {
        int e = base + r * FUSE_THREADS + threadIdx.x;
        if (e < E) {
            int d = dst[e];
            int b = d >> BUCKET_SHIFT;
            int rk = atomicAdd(&lcnt[b], 1);
            w0[r] = (unsigned)src[e] | ((unsigned)(d & (BUCKET_NODES - 1)) << 20);
            w1[r] = val[e];
            br[r] = (b << 16) | rk;
        } else {
            br[r] = -1;
        }
    }
    __syncthreads();
    for (int i = threadIdx.x; i < nbuckets; i += FUSE_THREADS) {
        int c = lcnt[i];
        lbase[i] = c ? atomicAdd(&gcnt[i], c) : 0;
    }
    __syncthreads();
    #pragma unroll
    for (int r = 0; r < K2_EPT; ++r) {
        if (br[r] >= 0) {
            int b  = br[r] >> 16;
            int rk = br[r] & 0xffff;
            edges[(size_t)b * EDGE_CAP + lbase[b] + rk] =
                make_uint2(w0[r], __float_as_uint(w1[r]));
        }
    }
}

// ---- K2: counting-sort each bucket slice by node, in place; emit deg/offsets ----
__global__ __launch_bounds__(SORT_THREADS)
void bucket_sort_kernel(uint2* __restrict__ edges,
                        const int* __restrict__ gcnt,
                        int* __restrict__ deg,
                        int* __restrict__ offsets,
                        int N) {
    __shared__ int hist[BUCKET_NODES];
    __shared__ int scan[BUCKET_NODES];
    int b = blockIdx.x;
    int cnt = gcnt[b];
    uint2* ep = edges + (size_t)b * EDGE_CAP;

    if (threadIdx.x < BUCKET_NODES) hist[threadIdx.x] = 0;
    __syncthreads();

    uint2 ed[SORT_EPT];
    int   rk[SORT_EPT];
    int   dl[SORT_EPT];
    #pragma unroll
    for (int r = 0; r < SORT_EPT; ++r) {
        int i = r * SORT_THREADS + threadIdx.x;
        if (i < cnt) {
            uint2 t = ep[i];
            int d = (int)(t.x >> 20);
            ed[r] = t;
            dl[r] = d;
            rk[r] = atomicAdd(&hist[d], 1);
        } else {
            dl[r] = -1;
        }
    }
    __syncthreads();

    if (threadIdx.x < BUCKET_NODES) scan[threadIdx.x] = hist[threadIdx.x];
    __syncthreads();
    #pragma unroll
    for (int off = 1; off < BUCKET_NODES; off <<= 1) {
        int v = 0;
        if (threadIdx.x < BUCKET_NODES && threadIdx.x >= off) v = scan[threadIdx.x - off];
        __syncthreads();
        if (threadIdx.x < BUCKET_NODES) scan[threadIdx.x] += v;
        __syncthreads();
    }

    int node0 = b << BUCKET_SHIFT;
    if (threadIdx.x < BUCKET_NODES) {
        int n = node0 + threadIdx.x;
        if (n < N) {
            deg[n]     = hist[threadIdx.x];
            offsets[n] = b * EDGE_CAP + scan[threadIdx.x] - hist[threadIdx.x];
        }
    }
    __syncthreads();

    #pragma unroll
    for (int r = 0; r < SORT_EPT; ++r) {
        if (dl[r] >= 0) {
            int p = scan[dl[r]] - hist[dl[r]] + rk[r];
            ep[p] = ed[r];
        }
    }
}

// ---- K3: fused gather + diag-w + LayerNorm (+ReLU) ----
// wave per node; 4 x 16-lane groups each fetch one full bf16 row (uint4/lane)
// => 4 edges and 1KB in flight per load instruction.
__global__ void gather_ln_kernel(const unsigned int* __restrict__ h2,
                                 const int* __restrict__ offsets,
                                 const int* __restrict__ deg,
                                 const uint2* __restrict__ edge_s,
                                 const float* __restrict__ w,
                                 const float* __restrict__ g,
                                 const float* __restrict__ bb,
                                 float* __restrict__ out_f32,
                                 unsigned int* __restrict__ out_b2,
                                 int N, int mode) {
    int node = blockIdx.x * (blockDim.x >> 6) + (threadIdx.x >> 6);
    int lane = threadIdx.x & 63;
    if (node >= N) return;

    int q  = lane >> 4;          // edge sub-group 0..3
    int sl = lane & 15;          // sublane within group

    int start = offsets[node];
    int cnt   = deg[node];

    const uint4* h4 = (const uint4*)h2;
    float aA0 = 0.f, aA1 = 0.f, aA2 = 0.f, aA3 = 0.f;   // feats 4sl+t
    float aB0 = 0.f, aB1 = 0.f, aB2 = 0.f, aB3 = 0.f;   // feats 4sl+t+64

    for (int base = 0; base < cnt; base += 64) {
        int m = min(64, cnt - base);
        unsigned e0 = 0u, e1 = 0u;
        if (lane < m) { uint2 t = edge_s[start + base + lane]; e0 = t.x; e1 = t.y; }
        for (int j = 0; j < m; j += 4) {
            int idx = j + q;     // <= 63 always
            int   s = __shfl((int)e0, idx, 64) & 0xfffff;   // lanes >= m hold 0 -> v=0
            float v = __uint_as_float((unsigned)__shfl((int)e1, idx, 64));
            uint4 hw = h4[(size_t)s * 16 + sl];
            aA0 = fmaf(v, lo_b2(hw.x), aA0);  aB0 = fmaf(v, hi_b2(hw.x), aB0);
            aA1 = fmaf(v, lo_b2(hw.y), aA1);  aB1 = fmaf(v, hi_b2(hw.y), aB1);
            aA2 = fmaf(v, lo_b2(hw.z), aA2);  aB2 = fmaf(v, hi_b2(hw.z), aB2);
            aA3 = fmaf(v, lo_b2(hw.w), aA3);  aB3 = fmaf(v, hi_b2(hw.w), aB3);
        }
    }

    // combine the 4 sub-groups (same feats live at lanes sl, sl+16, sl+32, sl+48)
    aA0 += __shfl_xor(aA0, 16, 64); aA0 += __shfl_xor(aA0, 32, 64);
    aA1 += __shfl_xor(aA1, 16, 64); aA1 += __shfl_xor(aA1, 32, 64);
    aA2 += __shfl_xor(aA2, 16, 64); aA2 += __shfl_xor(aA2, 32, 64);
    aA3 += __shfl_xor(aA3, 16, 64); aA3 += __shfl_xor(aA3, 32, 64);
    aB0 += __shfl_xor(aB0, 16, 64); aB0 += __shfl_xor(aB0, 32, 64);
    aB1 += __shfl_xor(aB1, 16, 64); aB1 += __shfl_xor(aB1, 32, 64);
    aB2 += __shfl_xor(aB2, 16, 64); aB2 += __shfl_xor(aB2, 32, 64);
    aB3 += __shfl_xor(aB3, 16, 64); aB3 += __shfl_xor(aB3, 32, 64);

    float4 wA = ((const float4*)w)[sl];
    float4 wB = ((const float4*)(w + 64))[sl];
    aA0 *= wA.x; aA1 *= wA.y; aA2 *= wA.z; aA3 *= wA.w;
    aB0 *= wB.x; aB1 *= wB.y; aB2 *= wB.z; aB3 *= wB.w;

    float sum = ((aA0 + aA1) + (aA2 + aA3)) + ((aB0 + aB1) + (aB2 + aB3));
    sum += __shfl_xor(sum, 1, 64); sum += __shfl_xor(sum, 2, 64);
    sum += __shfl_xor(sum, 4, 64); sum += __shfl_xor(sum, 8, 64);
    float mu = sum * (1.0f / D);

    float dA0 = aA0 - mu, dA1 = aA1 - mu, dA2 = aA2 - mu, dA3 = aA3 - mu;
    float dB0 = aB0 - mu, dB1 = aB1 - mu, dB2 = aB2 - mu, dB3 = aB3 - mu;
    float sq = ((dA0*dA0 + dA1*dA1) + (dA2*dA2 + dA3*dA3))
             + ((dB0*dB0 + dB1*dB1) + (dB2*dB2 + dB3*dB3));
    sq += __shfl_xor(sq, 1, 64); sq += __shfl_xor(sq, 2, 64);
    sq += __shfl_xor(sq, 4, 64); sq += __shfl_xor(sq, 8, 64);
    float rstd = rsqrtf(sq * (1.0f / D) + LN_EPS);

    float4 gA = ((const float4*)g)[sl];
    float4 gB = ((const float4*)(g + 64))[sl];
    float4 bA = ((const float4*)bb)[sl];
    float4 bB = ((const float4*)(bb + 64))[sl];
    float oA0 = dA0 * rstd * gA.x + bA.x, oA1 = dA1 * rstd * gA.y + bA.y;
    float oA2 = dA2 * rstd * gA.z + bA.z, oA3 = dA3 * rstd * gA.w + bA.w;
    float oB0 = dB0 * rstd * gB.x + bB.x, oB1 = dB1 * rstd * gB.y + bB.y;
    float oB2 = dB2 * rstd * gB.z + bB.z, oB3 = dB3 * rstd * gB.w + bB.w;

    if (mode == 1) {
        oA0 = fmaxf(oA0, 0.f); oA1 = fmaxf(oA1, 0.f);
        oA2 = fmaxf(oA2, 0.f); oA3 = fmaxf(oA3, 0.f);
        oB0 = fmaxf(oB0, 0.f); oB1 = fmaxf(oB1, 0.f);
        oB2 = fmaxf(oB2, 0.f); oB3 = fmaxf(oB3, 0.f);
        if (q == 0) {
            uint4 pw;
            pw.x = pack_b2(oA0, oB0); pw.y = pack_b2(oA1, oB1);
            pw.z = pack_b2(oA2, oB2); pw.w = pack_b2(oA3, oB3);
            ((uint4*)(out_b2 + (size_t)node * 64))[sl] = pw;
        }
    } else {
        if (q == 0) {
            ((float4*)(out_f32 + (size_t)node * D))[sl]      = make_float4(oA0, oA1, oA2, oA3);
            ((float4*)(out_f32 + (size_t)node * D + 64))[sl] = make_float4(oB0, oB1, oB2, oB3);
        }
    }
}

extern "C" void kernel_launch(void* const* d_in, const int* in_sizes, int n_in,
                              void* d_out, int out_size, void* d_ws, size_t ws_size,
                              hipStream_t stream) {
    const float* x    = (const float*)d_in[0];
    const int*   esrc = (const int*)d_in[1];
    const int*   edst = (const int*)d_in[2];
    const float* eval_= (const float*)d_in[3];
    const float* w1   = (const float*)d_in[4];
    const float* w2   = (const float*)d_in[5];
    const float* g1   = (const float*)d_in[6];
    const float* b1   = (const float*)d_in[7];
    const float* g2   = (const float*)d_in[8];
    const float* b2   = (const float*)d_in[9];
    float* out = (float*)d_out;

    const int N = in_sizes[0] / D;   // 100000
    const int E = in_sizes[1];       // 1600000
    const int nbuckets = (N + BUCKET_NODES - 1) >> BUCKET_SHIFT;   // 782

    unsigned int* xb      = (unsigned int*)d_ws;                 // 25.6 MB
    unsigned int* hb      = xb + (size_t)N * 64;                 // 25.6 MB
    uint2*        edges   = (uint2*)(hb + (size_t)N * 64);       // 25.6 MB
    int*          gcnt    = (int*)(edges + (size_t)nbuckets * EDGE_CAP);
    int*          deg     = gcnt + nbuckets;
    int*          offsets = deg + N;

    const int nwords = N * 64;
    const int conv_blocks = (nwords + FUSE_THREADS - 1) / FUSE_THREADS;
    const int fill_blocks = (E + FUSE_THREADS * K2_EPT - 1) / (FUSE_THREADS * K2_EPT);
    const int ggrid = (N + 3) / 4;   // 4 waves/block, wave per node

    hipMemsetAsync(gcnt, 0, (size_t)nbuckets * sizeof(int), stream);
    conv_fill_kernel<<<conv_blocks + fill_blocks, FUSE_THREADS, 0, stream>>>(
        x, xb, nwords, conv_blocks, esrc, edst, eval_, gcnt, edges, E, nbuckets);
    bucket_sort_kernel<<<nbuckets, SORT_THREADS, 0, stream>>>(edges, gcnt,
                                                              deg, offsets, N);
    // layer 1: gather(xb)*w1 -> LN -> ReLU -> hb (bf16 split)
    gather_ln_kernel<<<ggrid, 256, 0, stream>>>(xb, offsets, deg, edges,
                                                w1, g1, b1, nullptr, hb, N, 1);
    // layer 2: gather(hb)*w2 -> LN -> out (f32)
    gather_ln_kernel<<<ggrid, 256, 0, stream>>>(hb, offsets, deg, edges,
                                                w2, g2, b2, out, nullptr, N, 0);
}

// Round 8
// 295.880 us; speedup vs baseline: 9.9815x; 1.0427x over previous
//
#include <hip/hip_runtime.h>

typedef __fp16 half2_t __attribute__((ext_vector_type(2)));

#define D 128
#define LN_EPS 1e-5f
#define BUCKET_NODES 128
#define BUCKET_SHIFT 7
#define EDGE_CAP 4096          // avg ~2046 edges/bucket, sigma ~45; 45-sigma headroom
#define FUSE_THREADS 512
#define K2_EPT 16              // 8192 edges per fill block
#define GT 1024                // gather block threads (16 waves)

// split-f16 packing: word f of a row holds (feat f, feat f+64) as packed f16
__device__ inline unsigned pack_h2(float a, float b) {
    half2_t p = __builtin_amdgcn_cvt_pkrtz(a, b);
    return __builtin_bit_cast(unsigned, p);
}

// ---- K1: stitched  conv (x f32 -> xb split-f16)  +  coarse bucket fill ----
__global__ __launch_bounds__(FUSE_THREADS)
void conv_fill_kernel(const float* __restrict__ x, unsigned int* __restrict__ xb,
                      int nwords, int conv_blocks,
                      const int* __restrict__ src, const int* __restrict__ dst,
                      const float* __restrict__ val,
                      int* __restrict__ gcnt, uint2* __restrict__ edges,
                      int E, int nbuckets) {
    if ((int)blockIdx.x < conv_blocks) {
        int i = blockIdx.x * FUSE_THREADS + threadIdx.x;
        if (i < nwords) {
            int node = i >> 6, f = i & 63;
            xb[i] = pack_h2(x[(size_t)node * D + f], x[(size_t)node * D + 64 + f]);
        }
        return;
    }
    // fill: per-block LDS hist -> one reservation atomic per bucket ->
    // per-block contiguous write runs (line-dense)
    __shared__ int lcnt[1024];
    __shared__ int lbase[1024];
    int fb = (int)blockIdx.x - conv_blocks;
    for (int i = threadIdx.x; i < nbuckets; i += FUSE_THREADS) lcnt[i] = 0;
    __syncthreads();

    int base = fb * (FUSE_THREADS * K2_EPT);
    unsigned int w0[K2_EPT];
    float        w1[K2_EPT];
    int          br[K2_EPT];   // (bucket<<16)|rank, or -1
    #pragma unroll
    for (int r = 0; r < K2_EPT; ++r) {
        int e = base + r * FUSE_THREADS + threadIdx.x;
        if (e < E) {
            int d = dst[e];
            int b = d >> BUCKET_SHIFT;
            int rk = atomicAdd(&lcnt[b], 1);
            w0[r] = (unsigned)src[e] | ((unsigned)(d & (BUCKET_NODES - 1)) << 20);
            w1[r] = val[e];
            br[r] = (b << 16) | rk;
        } else {
            br[r] = -1;
        }
    }
    __syncthreads();
    for (int i = threadIdx.x; i < nbuckets; i += FUSE_THREADS) {
        int c = lcnt[i];
        lbase[i] = c ? atomicAdd(&gcnt[i], c) : 0;
    }
    __syncthreads();
    #pragma unroll
    for (int r = 0; r < K2_EPT; ++r) {
        if (br[r] >= 0) {
            int b  = br[r] >> 16;
            int rk = br[r] & 0xffff;
            edges[(size_t)b * EDGE_CAP + lbase[b] + rk] =
                make_uint2(w0[r], __float_as_uint(w1[r]));
        }
    }
}

// ---- K2: block per bucket: LDS counting-sort + gather + diag-w + LN (+ReLU) ----
// 16-lane group = one node (4 nodes/wave). Lane sl covers feats
// {4sl..4sl+3} u {64+4sl..64+4sl+3} via split-f16 uint4 row loads.
__global__ __launch_bounds__(GT, 8)
void gather_ln_kernel(const uint4* __restrict__ h4,
                      const int* __restrict__ gcnt,
                      const uint2* __restrict__ edges_g,
                      const float* __restrict__ w,
                      const float* __restrict__ g,
                      const float* __restrict__ bb,
                      float* __restrict__ out_f32,
                      unsigned int* __restrict__ out_h,
                      int N, int mode) {
    __shared__ uint2 eL[EDGE_CAP];          // 32 KB sorted edge list
    __shared__ int hist[BUCKET_NODES];
    __shared__ int scanb[BUCKET_NODES];
    __shared__ int obase[BUCKET_NODES];

    int bkt = blockIdx.x;
    int tid = threadIdx.x;
    int cnt = min(gcnt[bkt], EDGE_CAP);
    const uint2* ep = edges_g + (size_t)bkt * EDGE_CAP;

    if (tid < BUCKET_NODES) hist[tid] = 0;
    __syncthreads();

    uint2 ed[4]; int dl[4]; int rk[4];
    #pragma unroll
    for (int r = 0; r < 4; ++r) {
        int i = r * GT + tid;
        if (i < cnt) {
            uint2 t = ep[i];
            ed[r] = t;
            dl[r] = (int)(t.x >> 20);
            rk[r] = atomicAdd(&hist[dl[r]], 1);
        } else dl[r] = -1;
    }
    __syncthreads();
    if (tid < BUCKET_NODES) scanb[tid] = hist[tid];
    __syncthreads();
    #pragma unroll
    for (int off = 1; off < BUCKET_NODES; off <<= 1) {
        int v = 0;
        if (tid < BUCKET_NODES && tid >= off) v = scanb[tid - off];
        __syncthreads();
        if (tid < BUCKET_NODES) scanb[tid] += v;
        __syncthreads();
    }
    if (tid < BUCKET_NODES) obase[tid] = scanb[tid] - hist[tid];
    __syncthreads();
    #pragma unroll
    for (int r = 0; r < 4; ++r)
        if (dl[r] >= 0) eL[obase[dl[r]] + rk[r]] = ed[r];
    __syncthreads();

    int wid = tid >> 6, lane = tid & 63, grp = lane >> 4, sl = lane & 15;

    float4 wA = ((const float4*)w)[sl];
    float4 wB = ((const float4*)(w + 64))[sl];
    float4 gA = ((const float4*)g)[sl];
    float4 gB = ((const float4*)(g + 64))[sl];
    float4 bA = ((const float4*)bb)[sl];
    float4 bB = ((const float4*)(bb + 64))[sl];

    #pragma unroll
    for (int k = 0; k < 2; ++k) {
        int ni = k * 64 + wid * 4 + grp;            // 0..127
        int n = (bkt << BUCKET_SHIFT) + ni;
        if (n >= N) continue;
        int st = obase[ni], m = hist[ni];

        float aA0=0,aA1=0,aA2=0,aA3=0, aB0=0,aB1=0,aB2=0,aB3=0;
        for (int j = 0; j < m; j += 2) {
            uint2 tA = eL[st + j];                  // group-uniform: LDS broadcast
            uint2 tB = (j + 1 < m) ? eL[st + j + 1] : make_uint2(0u, 0u);
            int   sA = (int)(tA.x & 0xfffffu);
            float vA = __uint_as_float(tA.y);
            int   sB = (int)(tB.x & 0xfffffu);
            float vB = __uint_as_float(tB.y);       // 0 on pad -> no contribution
            uint4 hA = h4[(size_t)sA * 16 + sl];
            uint4 hB = h4[(size_t)sB * 16 + sl];
            half2_t p;
            p = __builtin_bit_cast(half2_t, hA.x);
            aA0 = fmaf(vA, (float)p.x, aA0); aB0 = fmaf(vA, (float)p.y, aB0);
            p = __builtin_bit_cast(half2_t, hA.y);
            aA1 = fmaf(vA, (float)p.x, aA1); aB1 = fmaf(vA, (float)p.y, aB1);
            p = __builtin_bit_cast(half2_t, hA.z);
            aA2 = fmaf(vA, (float)p.x, aA2); aB2 = fmaf(vA, (float)p.y, aB2);
            p = __builtin_bit_cast(half2_t, hA.w);
            aA3 = fmaf(vA, (float)p.x, aA3); aB3 = fmaf(vA, (float)p.y, aB3);
            p = __builtin_bit_cast(half2_t, hB.x);
            aA0 = fmaf(vB, (float)p.x, aA0); aB0 = fmaf(vB, (float)p.y, aB0);
            p = __builtin_bit_cast(half2_t, hB.y);
            aA1 = fmaf(vB, (float)p.x, aA1); aB1 = fmaf(vB, (float)p.y, aB1);
            p = __builtin_bit_cast(half2_t, hB.z);
            aA2 = fmaf(vB, (float)p.x, aA2); aB2 = fmaf(vB, (float)p.y, aB2);
            p = __builtin_bit_cast(half2_t, hB.w);
            aA3 = fmaf(vB, (float)p.x, aA3); aB3 = fmaf(vB, (float)p.y, aB3);
        }

        aA0 *= wA.x; aA1 *= wA.y; aA2 *= wA.z; aA3 *= wA.w;
        aB0 *= wB.x; aB1 *= wB.y; aB2 *= wB.z; aB3 *= wB.w;

        // LN over 128 feats: intra-lane 8 + 4 shfl_xor within the 16-lane group
        float sum = ((aA0 + aA1) + (aA2 + aA3)) + ((aB0 + aB1) + (aB2 + aB3));
        sum += __shfl_xor(sum, 1, 64); sum += __shfl_xor(sum, 2, 64);
        sum += __shfl_xor(sum, 4, 64); sum += __shfl_xor(sum, 8, 64);
        float mu = sum * (1.0f / D);

        float dA0 = aA0 - mu, dA1 = aA1 - mu, dA2 = aA2 - mu, dA3 = aA3 - mu;
        float dB0 = aB0 - mu, dB1 = aB1 - mu, dB2 = aB2 - mu, dB3 = aB3 - mu;
        float sq = ((dA0*dA0 + dA1*dA1) + (dA2*dA2 + dA3*dA3))
                 + ((dB0*dB0 + dB1*dB1) + (dB2*dB2 + dB3*dB3));
        sq += __shfl_xor(sq, 1, 64); sq += __shfl_xor(sq, 2, 64);
        sq += __shfl_xor(sq, 4, 64); sq += __shfl_xor(sq, 8, 64);
        float rstd = rsqrtf(sq * (1.0f / D) + LN_EPS);

        float oA0 = dA0 * rstd * gA.x + bA.x, oA1 = dA1 * rstd * gA.y + bA.y;
        float oA2 = dA2 * rstd * gA.z + bA.z, oA3 = dA3 * rstd * gA.w + bA.w;
        float oB0 = dB0 * rstd * gB.x + bB.x, oB1 = dB1 * rstd * gB.y + bB.y;
        float oB2 = dB2 * rstd * gB.z + bB.z, oB3 = dB3 * rstd * gB.w + bB.w;

        if (mode == 1) {
            oA0 = fmaxf(oA0, 0.f); oA1 = fmaxf(oA1, 0.f);
            oA2 = fmaxf(oA2, 0.f); oA3 = fmaxf(oA3, 0.f);
            oB0 = fmaxf(oB0, 0.f); oB1 = fmaxf(oB1, 0.f);
            oB2 = fmaxf(oB2, 0.f); oB3 = fmaxf(oB3, 0.f);
            uint4 pw;
            pw.x = pack_h2(oA0, oB0); pw.y = pack_h2(oA1, oB1);
            pw.z = pack_h2(oA2, oB2); pw.w = pack_h2(oA3, oB3);
            ((uint4*)(out_h + (size_t)n * 64))[sl] = pw;
        } else {
            ((float4*)(out_f32 + (size_t)n * D))[sl]      = make_float4(oA0, oA1, oA2, oA3);
            ((float4*)(out_f32 + (size_t)n * D + 64))[sl] = make_float4(oB0, oB1, oB2, oB3);
        }
    }
}

extern "C" void kernel_launch(void* const* d_in, const int* in_sizes, int n_in,
                              void* d_out, int out_size, void* d_ws, size_t ws_size,
                              hipStream_t stream) {
    const float* x    = (const float*)d_in[0];
    const int*   esrc = (const int*)d_in[1];
    const int*   edst = (const int*)d_in[2];
    const float* eval_= (const float*)d_in[3];
    const float* w1   = (const float*)d_in[4];
    const float* w2   = (const float*)d_in[5];
    const float* g1   = (const float*)d_in[6];
    const float* b1   = (const float*)d_in[7];
    const float* g2   = (const float*)d_in[8];
    const float* b2   = (const float*)d_in[9];
    float* out = (float*)d_out;

    const int N = in_sizes[0] / D;   // 100000
    const int E = in_sizes[1];       // 1600000
    const int nbuckets = (N + BUCKET_NODES - 1) >> BUCKET_SHIFT;   // 782

    unsigned int* xb    = (unsigned int*)d_ws;                 // 25.6 MB
    unsigned int* hb    = xb + (size_t)N * 64;                 // 25.6 MB
    uint2*        edges = (uint2*)(hb + (size_t)N * 64);       // 25.6 MB
    int*          gcnt  = (int*)(edges + (size_t)nbuckets * EDGE_CAP);

    const int nwords = N * 64;
    const int conv_blocks = (nwords + FUSE_THREADS - 1) / FUSE_THREADS;
    const int fill_blocks = (E + FUSE_THREADS * K2_EPT - 1) / (FUSE_THREADS * K2_EPT);

    (void)hipMemsetAsync(gcnt, 0, (size_t)nbuckets * sizeof(int), stream);
    conv_fill_kernel<<<conv_blocks + fill_blocks, FUSE_THREADS, 0, stream>>>(
        x, xb, nwords, conv_blocks, esrc, edst, eval_, gcnt, edges, E, nbuckets);
    // layer 1: sort+gather(xb)*w1 -> LN -> ReLU -> hb (f16 split)
    gather_ln_kernel<<<nbuckets, GT, 0, stream>>>((const uint4*)xb, gcnt, edges,
                                                  w1, g1, b1, nullptr, hb, N, 1);
    // layer 2: sort+gather(hb)*w2 -> LN -> out (f32)
    gather_ln_kernel<<<nbuckets, GT, 0, stream>>>((const uint4*)hb, gcnt, edges,
                                                  w2, g2, b2, out, nullptr, N, 0);
}